// Round 8
// baseline (163.819 us; speedup 1.0000x reference)
//
#include <hip/hip_runtime.h>

typedef unsigned short u16;
typedef unsigned int u32;
typedef unsigned long long u64;
typedef short short8 __attribute__((ext_vector_type(8)));   // 8 bf16 (4 VGPRs)
typedef float f32x4 __attribute__((ext_vector_type(4)));

#define DEV static __device__ __forceinline__

DEV float ex2(float x){ return __builtin_amdgcn_exp2f(x); }
DEV float rcpf_(float x){ return __builtin_amdgcn_rcpf(x); }
DEV float bf2f(u16 v){ union {u32 u; float f;} c; c.u=((u32)v)<<16; return c.f; }
DEV u16 f2bf(float f){ union {u32 u; float f;} c; c.f=f; u32 r=c.u+0x7fffu+((c.u>>16)&1u); return (u16)(r>>16); }

// prescaled activations: weights/biases already carry the log2e factors
DEV float tanh_ps(float v){          // v = 2*log2e*z ; tanh(z) = 1 - 2/(2^v+1)
    float t = ex2(v);
    return 1.f - 2.f*rcpf_(t+1.f);
}
DEV float sigm_ps(float v){          // v = -log2e*z ; sigma(z) = 1/(1+2^v)
    return rcpf_(1.f + ex2(v));
}
DEV u32 cvtpk(float lo, float hi){   // u32 = bf16(hi)<<16 | bf16(lo), RNE
    u32 r;
    asm("v_cvt_pk_bf16_f32 %0, %1, %2" : "=v"(r) : "v"(lo), "v"(hi));
    return r;
}
DEV short8 ld8(const u16* p){        // 8 consecutive u16 from LDS (8B-aligned)
    union { u64 q[2]; short8 v; } u;
    u.q[0] = *(const u64*)(p);
    u.q[1] = *(const u64*)(p+4);
    return u.v;
}
DEV float4 ld4u(const float* p){     // 4B-aligned float4 (global_load_dwordx4)
    float4 v; __builtin_memcpy(&v, p, 16); return v;
}
DEV f32x4 mfma16(short8 a, short8 b, f32x4 c){
    return __builtin_amdgcn_mfma_f32_16x16x32_bf16(a, b, c, 0, 0, 0);
}
#define LGKM0() asm volatile("s_waitcnt lgkmcnt(0)" ::: "memory")

// ---------------- weight prep: pack PRESCALED fragments + biases into d_ws
// ws layout: u16 frag[32768] | f32 bias[528] @16384 | f32 l1 m1_w48,m1_b16,m2_w48,m2_b16 @16912..17039
// 8 MFMA layers l: M1L2,M1L3,M1L4,M1L5, M2L2,M2L3,M2L4,M2L5
// frag elem (kt,ct,lane,i): k=kt*32+(lane>>4)*8+i, n=ct*16+(lane&15); zero-padded
struct PrepArgs { const float* w[8]; const float* b[8]; const float* l1w[2]; const float* l1b[2]; };

__global__ void prep_kernel(PrepArgs pa, float* ws){
    u16* whi = (u16*)ws;
    float* bo = ws + 16384;
    const int K_[8]  = {16,32,64,128, 16,32,64,128};
    const int N_[8]  = {32,64,128,64, 32,64,128,1};
    const int NT_[8] = {2,4,8,4, 2,4,8,1};
    const int FB_[8] = {0,1024,3072,11264, 19456,20480,22528,30720};
    const int BB_[8] = {0,32,96,224, 288,320,384,512};
    const float CT_ = 2.8853900817779268f;    // 2*log2(e)  (tanh layers)
    const float CS_ = -1.4426950408889634f;   // -log2(e)   (sigmoid heads)
    const float SC_[8] = {CT_,CT_,CT_,CS_, CT_,CT_,CT_,CS_};
    int tid = blockIdx.x*256 + threadIdx.x;
    if (tid < 32768){
        int l = 0;
#pragma unroll
        for (int i=1;i<8;++i) if (tid >= FB_[i]) l = i;
        int idx = tid - FB_[l];
        int ktnt = idx >> 9;
        int nt = ktnt % NT_[l], kt = ktnt / NT_[l];
        int lane = (idx >> 3) & 63;
        int i = idx & 7;
        int k = kt*32 + ((lane>>4)<<3) + i;
        int n = nt*16 + (lane&15);
        const float* wsrc = pa.w[l];
        float v = (k < K_[l] && n < N_[l]) ? SC_[l]*wsrc[k*N_[l] + n] : 0.f;
        whi[tid] = f2bf(v);
    } else if (tid < 32768 + 528){
        int t = tid - 32768;
        int l = 0;
#pragma unroll
        for (int i=1;i<8;++i) if (t >= BB_[i]) l = i;
        int n = t - BB_[l];
        bo[t] = (n < N_[l]) ? SC_[l]*pa.b[l][n] : 0.f;
    } else if (tid < 33296 + 128){
        int t = tid - 33296;
        if (t < 48)       ws[16912+t]     = CT_*pa.l1w[0][t];
        else if (t < 64)  ws[16960+t-48]  = CT_*pa.l1b[0][t-48];
        else if (t < 112) ws[16976+t-64]  = CT_*pa.l1w[1][t-64];
        else              ws[17024+t-112] = CT_*pa.l1b[1][t-112];
    }
}

// ---------------- layer-1 (3->16, prescaled tanh) on VALU, + K-pad zero of ch16..31
DEV void l1_valu(float x0,float x1,float x2, const float* w, const float* bias,
                 u16* buf, int lane){
    int pxl = lane & 31, jb = (lane>>5)*8;
    float v[8];
#pragma unroll
    for (int j=0;j<8;++j){
        int jj = jb + j;
        v[j] = tanh_ps(bias[jj] + x0*w[jj] + x1*w[16+jj] + x2*w[32+jj]);
    }
    union { u32 d[2]; u64 q; } q0, q1;
    q0.d[0]=cvtpk(v[0],v[1]); q0.d[1]=cvtpk(v[2],v[3]);
    q1.d[0]=cvtpk(v[4],v[5]); q1.d[1]=cvtpk(v[6],v[7]);
    *(u64*)(buf + pxl*132 + jb)      = q0.q;
    *(u64*)(buf + pxl*132 + jb+4)    = q1.q;
    *(u64*)(buf + pxl*132 + 16+jb)   = 0ull;   // zero ch16..31 (layer-2 K-pad)
    *(u64*)(buf + pxl*132 + 16+jb+4) = 0ull;
}

// ---------------- swapped MFMA layer, IN-PLACE on one [32][132] buffer
// A=weights: row=out-ch=lane&15(+ct*16), k=(lane>>4)*8+i
// B=acts:    col=pixel=lane&15(+pt*16),  k=(lane>>4)*8+i
// D: col=pixel=lane&15, row=out-ch=(lane>>4)*4+r (+ct*16) -> cvt_pk x2 + ds_write_b64
// bias pre-loaded into accumulator (D row = channel -> exact float4 match).
// Reads complete before writes (program order + LDS per-wave FIFO) -> in-place safe.
// ACT: 0=tanh_ps, 1=sigm_ps, 2=raw channel0 -> sPre[px]
template<int KT, int CT, int ACT>
DEV void layer(u16* buf, const u16* wf, const float* bias, float* sPre, int lane){
    short8 x[2][KT];
    int col = lane & 15, koff = (lane>>4)<<3;
#pragma unroll
    for (int pt=0;pt<2;++pt)
#pragma unroll
    for (int kt=0;kt<KT;++kt)
        x[pt][kt] = ld8(buf + (pt*16 + col)*132 + kt*32 + koff);
    float4 bvs[CT];
#pragma unroll
    for (int ct=0;ct<CT;++ct){
        if constexpr (ACT==2){
            float b0 = bias[0];
            bvs[ct] = (float4){b0,b0,b0,b0};
        } else {
            bvs[ct] = *(const float4*)(bias + ct*16 + ((lane>>4)<<2));
        }
    }
    asm volatile("" ::: "memory");   // pin LDS read-before-write (in-place update)
#pragma unroll 2
    for (int ct=0; ct<CT; ++ct){
        f32x4 acc[2];
        acc[0]=(f32x4){bvs[ct].x,bvs[ct].y,bvs[ct].z,bvs[ct].w};
        acc[1]=acc[0];
#pragma unroll
        for (int kt=0;kt<KT;++kt){
            short8 wv = *(const short8*)(wf + (((kt*CT+ct)<<6) + lane)*8);
#pragma unroll
            for (int pt=0;pt<2;++pt) acc[pt] = mfma16(wv, x[pt][kt], acc[pt]);
        }
        if constexpr (ACT==2){
            if ((lane>>4)==0){ sPre[col]=acc[0][0]; sPre[16+col]=acc[1][0]; }
        } else {
            int chb = ct*16 + ((lane>>4)<<2);
#pragma unroll
            for (int pt=0;pt<2;++pt){
                float v0 = acc[pt][0];
                float v1 = acc[pt][1];
                float v2 = acc[pt][2];
                float v3 = acc[pt][3];
                if constexpr (ACT==0){
                    v0=tanh_ps(v0); v1=tanh_ps(v1); v2=tanh_ps(v2); v3=tanh_ps(v3);
                } else {
                    v0=sigm_ps(v0); v1=sigm_ps(v1); v2=sigm_ps(v2); v3=sigm_ps(v3);
                }
                union { u32 d[2]; u64 q; } qq;
                qq.d[0]=cvtpk(v0,v1); qq.d[1]=cvtpk(v2,v3);
                *(u64*)(buf + (pt*16 + col)*132 + chb) = qq.q;
            }
        }
    }
}

// 2 independent waves per block (disjoint LDS halves, no barriers)
__global__ __launch_bounds__(128, 4)
void dlut_kernel(const float* __restrict__ df, const float* __restrict__ lr,
                 const float* __restrict__ ws, float* __restrict__ out){
    constexpr int Hh=359, Ww=639, HW=Hh*Ww, NP=2*HW, LHW=360*640;
    __shared__ u16 sX[2][32][132];
    __shared__ float sPreA[2][32];

    const u16* whi = (const u16*)ws;
    const float* bo = ws + 16384;

    int wv   = threadIdx.x >> 6;
    int lane = threadIdx.x & 63;
    u16* buf   = &sX[wv][0][0];
    float* sPre = &sPreA[wv][0];

    int pxl = lane & 31, hv = lane >> 5;
    int p = blockIdx.x*64 + wv*32 + pxl;

    float x0=0.f, x1=0.f, x2=0.f;
    int b=0, r2=0, hh=0, wwp=0;
    if (p < NP){
        b = p/HW; r2 = p - b*HW; hh = r2/Ww; wwp = r2 - hh*Ww;
        x0 = df[(b*3+0)*HW + r2];
        x1 = df[(b*3+1)*HW + r2];
        x2 = df[(b*3+2)*HW + r2];
    }

    // ===== MLP2 (scale head) =====
    l1_valu(x0,x1,x2, ws+16976, ws+17024, buf, lane);
    LGKM0();
    layer<1,2,0>(buf, whi+19456, bo+288, sPre, lane);
    LGKM0();
    layer<1,4,0>(buf, whi+20480, bo+320, sPre, lane);
    LGKM0();
    layer<2,8,0>(buf, whi+22528, bo+384, sPre, lane);
    LGKM0();
    layer<4,1,2>(buf, whi+30720, bo+512, sPre, lane);
    LGKM0();
    // ===== MLP1 (F_r head) =====
    l1_valu(x0,x1,x2, ws+16912, ws+16960, buf, lane);
    LGKM0();
    layer<1,2,0>(buf, whi+0,     bo+0,   sPre, lane);
    LGKM0();
    layer<1,4,0>(buf, whi+1024,  bo+32,  sPre, lane);
    LGKM0();
    layer<2,8,0>(buf, whi+3072,  bo+96,  sPre, lane);
    LGKM0();
    layer<4,4,1>(buf, whi+11264, bo+224, sPre, lane);
    LGKM0();
    // Fr (sigmoid'd bf16) in buf[px][0..63]; prescaled s pre-act in sPre[px]

    // ===== filters (separable Gaussian powers) + unfold + writes =====
    if (p < NP){
        float s = sigm_ps(sPre[pxl]) + 0.05f;
        // g = exp(-d2/(2s)) = E1^(16*d2), E1 = 2^(-log2e/(32 s)); 16*dy^2 in {1,9,25,49}
        float E1 = ex2(-0.045084220f * rcpf_(s));
        float F2=E1*E1, F4=F2*F2, F8=F4*F4, F16=F8*F8, F32=F16*F16;
        float F9=F8*E1, F25=F16*F9, F49=F32*F16*E1;
        // cy=1.25 -> rows {F25,E1,F9,F49}; cy=1.75 -> rows {F49,F9,E1,F25}
        bool hb = (hv!=0);          // d = hv*2+dd: dy-set = hv, dx-set = dd
        float ry[4];
        ry[0]= hb?F49:F25; ry[1]= hb?F9:E1; ry[2]= hb?E1:F9; ry[3]= hb?F25:F49;
        float cx0[4] = {F25,E1,F9,F49};
        float cx1[4] = {F49,F9,E1,F25};

        float pvv[3][16];
        bool interior = (hh>=1) & (hh<=357) & (wwp>=1) & (wwp<=637);
        if (interior){
            int base0 = (b*3)*LHW + (hh-1)*640 + (wwp-1);
#pragma unroll
            for (int c=0;c<3;++c){
#pragma unroll
                for (int ky=0;ky<4;++ky){
                    float4 v = ld4u(lr + base0 + c*LHW + ky*640);
                    pvv[c][ky*4+0]=v.x; pvv[c][ky*4+1]=v.y;
                    pvv[c][ky*4+2]=v.z; pvv[c][ky*4+3]=v.w;
                }
            }
        } else {
#pragma unroll
            for (int ky=0;ky<4;++ky){
                int yy=hh+ky-1;
                int yyc = yy<0?0:(yy>359?359:yy);
                bool oky = (yy>=0)&&(yy<360);
#pragma unroll
                for (int kx=0;kx<4;++kx){
                    int xx=wwp+kx-1;
                    int xxc = xx<0?0:(xx>639?639:xx);
                    bool ok = oky&&(xx>=0)&&(xx<640);
                    int k=ky*4+kx;
                    int base = (b*3)*LHW + yyc*640 + xxc;
#pragma unroll
                    for (int c=0;c<3;++c){
                        float v = lr[base + c*LHW];
                        pvv[c][k] = ok ? v : 0.f;
                    }
                }
            }
        }
#pragma unroll
        for (int dd=0; dd<2; ++dd){
            int d = hv*2 + dd;
            float t[16]; float gs=0.f, T=0.f;
#pragma unroll
            for (int k=0;k<16;++k){
                float cxv = (dd==0) ? cx0[k&3] : cx1[k&3];   // static index
                float gk = ry[k>>2]*cxv;
                float fr = bf2f(buf[pxl*132 + d*16+k]);
                float tk = gk*fr;
                gs += gk; T += tk;
                t[k] = tk;
            }
            // filt = g*fr/T, with exact s16 = rg*T + 1e-12 kept for output & final norm
            float rg = rcpf_(gs + 1e-12f);
            float s16v = T*rg + 1e-12f;
            float sc2 = rg * rcpf_(s16v);
            float y0=0.f,y1=0.f,y2=0.f;
#pragma unroll
            for (int k=0;k<16;++k){
                y0+=pvv[0][k]*t[k]; y1+=pvv[1][k]*t[k]; y2+=pvv[2][k]*t[k];
            }
            y0*=sc2; y1*=sc2; y2*=sc2;
            int dy=d>>1, dx=d&1;
            int rc = (2*hh+dy)*1278 + 2*wwp+dx;
            out[((b*3+0)*718)*1278 + rc] = y0;
            out[((b*3+1)*718)*1278 + rc] = y1;
            out[((b*3+2)*718)*1278 + rc] = y2;
            out[5505624 + ((b*4+d)*359 + hh)*639 + wwp] = s16v;
        }
    }
}

extern "C" void kernel_launch(void* const* d_in, const int* in_sizes, int n_in,
                              void* d_out, int out_size, void* d_ws, size_t ws_size,
                              hipStream_t stream){
    const float* df=(const float*)d_in[0];
    const float* lr=(const float*)d_in[1];
    // dict order per i: m1_w i -> d_in[2+4i], m1_b i -> [3+4i], m2_w i -> [4+4i], m2_b i -> [5+4i]
    PrepArgs pa;
    for (int i=0;i<4;++i){
        pa.w[i]   = (const float*)d_in[2+4*(i+1)];   // m1_w1..m1_w4
        pa.b[i]   = (const float*)d_in[3+4*(i+1)];   // m1_b1..m1_b4
        pa.w[4+i] = (const float*)d_in[4+4*(i+1)];   // m2_w1..m2_w4
        pa.b[4+i] = (const float*)d_in[5+4*(i+1)];   // m2_b1..m2_b4
    }
    pa.l1w[0] = (const float*)d_in[2];  pa.l1b[0] = (const float*)d_in[3];
    pa.l1w[1] = (const float*)d_in[4];  pa.l1b[1] = (const float*)d_in[5];

    float* ws = (float*)d_ws;
    hipLaunchKernelGGL(prep_kernel, dim3(131), dim3(256), 0, stream, pa, ws);

    constexpr int NP = 2*359*639;
    hipLaunchKernelGGL(dlut_kernel, dim3((NP+63)/64), dim3(128), 0, stream,
                       df, lr, (const float*)ws, (float*)d_out);
}

// Round 9
// 89.352 us; speedup vs baseline: 1.8334x; 1.8334x over previous
//
#include <hip/hip_runtime.h>

typedef unsigned short u16;
typedef unsigned int u32;
typedef unsigned long long u64;
typedef short short8 __attribute__((ext_vector_type(8)));   // 8 bf16 (4 VGPRs)
typedef float f32x4 __attribute__((ext_vector_type(4)));

#define DEV static __device__ __forceinline__

DEV float ex2(float x){ return __builtin_amdgcn_exp2f(x); }
DEV float rcpf_(float x){ return __builtin_amdgcn_rcpf(x); }
DEV float bf2f(u16 v){ union {u32 u; float f;} c; c.u=((u32)v)<<16; return c.f; }
DEV u16 f2bf(float f){ union {u32 u; float f;} c; c.f=f; u32 r=c.u+0x7fffu+((c.u>>16)&1u); return (u16)(r>>16); }

// prescaled activations: weights/biases already carry the log2e factors
DEV float tanh_ps(float v){          // v = 2*log2e*z ; tanh(z) = 1 - 2/(2^v+1)
    float t = ex2(v);
    return 1.f - 2.f*rcpf_(t+1.f);
}
DEV float sigm_ps(float v){          // v = -log2e*z ; sigma(z) = 1/(1+2^v)
    return rcpf_(1.f + ex2(v));
}
DEV u32 cvtpk(float lo, float hi){   // u32 = bf16(hi)<<16 | bf16(lo), RNE
    u32 r;
    asm("v_cvt_pk_bf16_f32 %0, %1, %2" : "=v"(r) : "v"(lo), "v"(hi));
    return r;
}
DEV short8 ld8(const u16* p){        // 8 consecutive u16 from LDS (8B-aligned)
    union { u64 q[2]; short8 v; } u;
    u.q[0] = *(const u64*)(p);
    u.q[1] = *(const u64*)(p+4);
    return u.v;
}
DEV float4 ld4u(const float* p){     // 4B-aligned float4 (global_load_dwordx4)
    float4 v; __builtin_memcpy(&v, p, 16); return v;
}
DEV f32x4 mfma16(short8 a, short8 b, f32x4 c){
    return __builtin_amdgcn_mfma_f32_16x16x32_bf16(a, b, c, 0, 0, 0);
}
#define LGKM0() asm volatile("s_waitcnt lgkmcnt(0)" ::: "memory")

// ---------------- weight prep: pack PRESCALED fragments + biases into d_ws
// ws layout: u16 frag[32768] | f32 bias[528] @16384 | f32 l1 m1_w48,m1_b16,m2_w48,m2_b16 @16912..17039
// 8 MFMA layers l: M1L2,M1L3,M1L4,M1L5, M2L2,M2L3,M2L4,M2L5
// frag elem (kt,ct,lane,i): k=kt*32+(lane>>4)*8+i, n=ct*16+(lane&15); zero-padded
struct PrepArgs { const float* w[8]; const float* b[8]; const float* l1w[2]; const float* l1b[2]; };

__global__ void prep_kernel(PrepArgs pa, float* ws){
    u16* whi = (u16*)ws;
    float* bo = ws + 16384;
    const int K_[8]  = {16,32,64,128, 16,32,64,128};
    const int N_[8]  = {32,64,128,64, 32,64,128,1};
    const int NT_[8] = {2,4,8,4, 2,4,8,1};
    const int FB_[8] = {0,1024,3072,11264, 19456,20480,22528,30720};
    const int BB_[8] = {0,32,96,224, 288,320,384,512};
    const float CT_ = 2.8853900817779268f;    // 2*log2(e)  (tanh layers)
    const float CS_ = -1.4426950408889634f;   // -log2(e)   (sigmoid heads)
    const float SC_[8] = {CT_,CT_,CT_,CS_, CT_,CT_,CT_,CS_};
    int tid = blockIdx.x*256 + threadIdx.x;
    if (tid < 32768){
        int l = 0;
#pragma unroll
        for (int i=1;i<8;++i) if (tid >= FB_[i]) l = i;
        int idx = tid - FB_[l];
        int ktnt = idx >> 9;
        int nt = ktnt % NT_[l], kt = ktnt / NT_[l];
        int lane = (idx >> 3) & 63;
        int i = idx & 7;
        int k = kt*32 + ((lane>>4)<<3) + i;
        int n = nt*16 + (lane&15);
        const float* wsrc = pa.w[l];
        float v = (k < K_[l] && n < N_[l]) ? SC_[l]*wsrc[k*N_[l] + n] : 0.f;
        whi[tid] = f2bf(v);
    } else if (tid < 32768 + 528){
        int t = tid - 32768;
        int l = 0;
#pragma unroll
        for (int i=1;i<8;++i) if (t >= BB_[i]) l = i;
        int n = t - BB_[l];
        bo[t] = (n < N_[l]) ? SC_[l]*pa.b[l][n] : 0.f;
    } else if (tid < 33296 + 128){
        int t = tid - 33296;
        if (t < 48)       ws[16912+t]     = CT_*pa.l1w[0][t];
        else if (t < 64)  ws[16960+t-48]  = CT_*pa.l1b[0][t-48];
        else if (t < 112) ws[16976+t-64]  = CT_*pa.l1w[1][t-64];
        else              ws[17024+t-112] = CT_*pa.l1b[1][t-112];
    }
}

// ---------------- layer-1 (3->16, prescaled tanh) on VALU, + K-pad zero of ch16..31
DEV void l1_valu(float x0,float x1,float x2, const float* w, const float* bias,
                 u16* buf, int lane){
    int pxl = lane & 31, jb = (lane>>5)*8;
    float v[8];
#pragma unroll
    for (int j=0;j<8;++j){
        int jj = jb + j;
        v[j] = tanh_ps(bias[jj] + x0*w[jj] + x1*w[16+jj] + x2*w[32+jj]);
    }
    union { u32 d[2]; u64 q; } q0, q1;
    q0.d[0]=cvtpk(v[0],v[1]); q0.d[1]=cvtpk(v[2],v[3]);
    q1.d[0]=cvtpk(v[4],v[5]); q1.d[1]=cvtpk(v[6],v[7]);
    *(u64*)(buf + pxl*132 + jb)      = q0.q;
    *(u64*)(buf + pxl*132 + jb+4)    = q1.q;
    *(u64*)(buf + pxl*132 + 16+jb)   = 0ull;   // zero ch16..31 (layer-2 K-pad)
    *(u64*)(buf + pxl*132 + 16+jb+4) = 0ull;
}

// ---------------- swapped MFMA layer, IN-PLACE on one [32][132] buffer
// A=weights: row=out-ch=lane&15(+ct*16), k=(lane>>4)*8+i
// B=acts:    col=pixel=lane&15(+pt*16),  k=(lane>>4)*8+i
// D: col=pixel=lane&15, row=out-ch=(lane>>4)*4+r (+ct*16) -> cvt_pk x2 + ds_write_b64
// bias loaded INSIDE the ct loop (runtime ct only in address math — never an
// array index; rule #20) and placed directly in the accumulator.
// Reads complete before writes (program order + LDS per-wave FIFO) -> in-place safe.
// ACT: 0=tanh_ps, 1=sigm_ps, 2=raw channel0 -> sPre[px]
template<int KT, int CT, int ACT>
DEV void layer(u16* buf, const u16* wf, const float* bias, float* sPre, int lane){
    short8 x[2][KT];
    int col = lane & 15, koff = (lane>>4)<<3;
#pragma unroll
    for (int pt=0;pt<2;++pt)
#pragma unroll
    for (int kt=0;kt<KT;++kt)
        x[pt][kt] = ld8(buf + (pt*16 + col)*132 + kt*32 + koff);
    asm volatile("" ::: "memory");   // pin LDS read-before-write (in-place update)
#pragma unroll 2
    for (int ct=0; ct<CT; ++ct){
        f32x4 acc[2];
        if constexpr (ACT==2){
            float b0 = bias[0];
            acc[0]=(f32x4){b0,b0,b0,b0};
        } else {
            float4 bv = *(const float4*)(bias + ct*16 + ((lane>>4)<<2));
            acc[0]=(f32x4){bv.x,bv.y,bv.z,bv.w};
        }
        acc[1]=acc[0];
#pragma unroll
        for (int kt=0;kt<KT;++kt){
            short8 wv = *(const short8*)(wf + (((kt*CT+ct)<<6) + lane)*8);
#pragma unroll
            for (int pt=0;pt<2;++pt) acc[pt] = mfma16(wv, x[pt][kt], acc[pt]);
        }
        if constexpr (ACT==2){
            if ((lane>>4)==0){ sPre[col]=acc[0][0]; sPre[16+col]=acc[1][0]; }
        } else {
            int chb = ct*16 + ((lane>>4)<<2);
#pragma unroll
            for (int pt=0;pt<2;++pt){
                float v0 = acc[pt][0];
                float v1 = acc[pt][1];
                float v2 = acc[pt][2];
                float v3 = acc[pt][3];
                if constexpr (ACT==0){
                    v0=tanh_ps(v0); v1=tanh_ps(v1); v2=tanh_ps(v2); v3=tanh_ps(v3);
                } else {
                    v0=sigm_ps(v0); v1=sigm_ps(v1); v2=sigm_ps(v2); v3=sigm_ps(v3);
                }
                union { u32 d[2]; u64 q; } qq;
                qq.d[0]=cvtpk(v0,v1); qq.d[1]=cvtpk(v2,v3);
                *(u64*)(buf + (pt*16 + col)*132 + chb) = qq.q;
            }
        }
    }
}

// 2 independent waves per block (disjoint LDS halves, no barriers)
__global__ __launch_bounds__(128, 4)
void dlut_kernel(const float* __restrict__ df, const float* __restrict__ lr,
                 const float* __restrict__ ws, float* __restrict__ out){
    constexpr int Hh=359, Ww=639, HW=Hh*Ww, NP=2*HW, LHW=360*640;
    __shared__ u16 sX[2][32][132];
    __shared__ float sPreA[2][32];

    const u16* whi = (const u16*)ws;
    const float* bo = ws + 16384;

    int wv   = threadIdx.x >> 6;
    int lane = threadIdx.x & 63;
    u16* buf   = &sX[wv][0][0];
    float* sPre = &sPreA[wv][0];

    int pxl = lane & 31, hv = lane >> 5;
    int p = blockIdx.x*64 + wv*32 + pxl;

    float x0=0.f, x1=0.f, x2=0.f;
    int b=0, r2=0, hh=0, wwp=0;
    if (p < NP){
        b = p/HW; r2 = p - b*HW; hh = r2/Ww; wwp = r2 - hh*Ww;
        x0 = df[(b*3+0)*HW + r2];
        x1 = df[(b*3+1)*HW + r2];
        x2 = df[(b*3+2)*HW + r2];
    }

    // ===== MLP2 (scale head) =====
    l1_valu(x0,x1,x2, ws+16976, ws+17024, buf, lane);
    LGKM0();
    layer<1,2,0>(buf, whi+19456, bo+288, sPre, lane);
    LGKM0();
    layer<1,4,0>(buf, whi+20480, bo+320, sPre, lane);
    LGKM0();
    layer<2,8,0>(buf, whi+22528, bo+384, sPre, lane);
    LGKM0();
    layer<4,1,2>(buf, whi+30720, bo+512, sPre, lane);
    LGKM0();
    // ===== MLP1 (F_r head) =====
    l1_valu(x0,x1,x2, ws+16912, ws+16960, buf, lane);
    LGKM0();
    layer<1,2,0>(buf, whi+0,     bo+0,   sPre, lane);
    LGKM0();
    layer<1,4,0>(buf, whi+1024,  bo+32,  sPre, lane);
    LGKM0();
    layer<2,8,0>(buf, whi+3072,  bo+96,  sPre, lane);
    LGKM0();
    layer<4,4,1>(buf, whi+11264, bo+224, sPre, lane);
    LGKM0();
    // Fr (sigmoid'd bf16) in buf[px][0..63]; prescaled s pre-act in sPre[px]

    // ===== filters (separable Gaussian powers) + unfold + writes =====
    if (p < NP){
        float s = sigm_ps(sPre[pxl]) + 0.05f;
        // g = exp(-d2/(2s)) = E1^(16*d2), E1 = 2^(-log2e/(32 s)); 16*dy^2 in {1,9,25,49}
        float E1 = ex2(-0.045084220f * rcpf_(s));
        float F2=E1*E1, F4=F2*F2, F8=F4*F4, F16=F8*F8, F32=F16*F16;
        float F9=F8*E1, F25=F16*F9, F49=F32*F16*E1;
        // cy=1.25 -> rows {F25,E1,F9,F49}; cy=1.75 -> rows {F49,F9,E1,F25}
        bool hb = (hv!=0);          // d = hv*2+dd: dy-set = hv, dx-set = dd
        float ry[4];
        ry[0]= hb?F49:F25; ry[1]= hb?F9:E1; ry[2]= hb?E1:F9; ry[3]= hb?F25:F49;
        float cx0[4] = {F25,E1,F9,F49};
        float cx1[4] = {F49,F9,E1,F25};

        float pvv[3][16];
        bool interior = (hh>=1) & (hh<=357) & (wwp>=1) & (wwp<=637);
        if (interior){
            int base0 = (b*3)*LHW + (hh-1)*640 + (wwp-1);
#pragma unroll
            for (int c=0;c<3;++c){
#pragma unroll
                for (int ky=0;ky<4;++ky){
                    float4 v = ld4u(lr + base0 + c*LHW + ky*640);
                    pvv[c][ky*4+0]=v.x; pvv[c][ky*4+1]=v.y;
                    pvv[c][ky*4+2]=v.z; pvv[c][ky*4+3]=v.w;
                }
            }
        } else {
#pragma unroll
            for (int ky=0;ky<4;++ky){
                int yy=hh+ky-1;
                int yyc = yy<0?0:(yy>359?359:yy);
                bool oky = (yy>=0)&&(yy<360);
#pragma unroll
                for (int kx=0;kx<4;++kx){
                    int xx=wwp+kx-1;
                    int xxc = xx<0?0:(xx>639?639:xx);
                    bool ok = oky&&(xx>=0)&&(xx<640);
                    int k=ky*4+kx;
                    int base = (b*3)*LHW + yyc*640 + xxc;
#pragma unroll
                    for (int c=0;c<3;++c){
                        float v = lr[base + c*LHW];
                        pvv[c][k] = ok ? v : 0.f;
                    }
                }
            }
        }
#pragma unroll
        for (int dd=0; dd<2; ++dd){
            int d = hv*2 + dd;
            float t[16]; float gs=0.f, T=0.f;
#pragma unroll
            for (int k=0;k<16;++k){
                float cxv = (dd==0) ? cx0[k&3] : cx1[k&3];   // static index
                float gk = ry[k>>2]*cxv;
                float fr = bf2f(buf[pxl*132 + d*16+k]);
                float tk = gk*fr;
                gs += gk; T += tk;
                t[k] = tk;
            }
            // filt = g*fr/T, with exact s16 = rg*T + 1e-12 kept for output & final norm
            float rg = rcpf_(gs + 1e-12f);
            float s16v = T*rg + 1e-12f;
            float sc2 = rg * rcpf_(s16v);
            float y0=0.f,y1=0.f,y2=0.f;
#pragma unroll
            for (int k=0;k<16;++k){
                y0+=pvv[0][k]*t[k]; y1+=pvv[1][k]*t[k]; y2+=pvv[2][k]*t[k];
            }
            y0*=sc2; y1*=sc2; y2*=sc2;
            int dy=d>>1, dx=d&1;
            int rc = (2*hh+dy)*1278 + 2*wwp+dx;
            out[((b*3+0)*718)*1278 + rc] = y0;
            out[((b*3+1)*718)*1278 + rc] = y1;
            out[((b*3+2)*718)*1278 + rc] = y2;
            out[5505624 + ((b*4+d)*359 + hh)*639 + wwp] = s16v;
        }
    }
}

extern "C" void kernel_launch(void* const* d_in, const int* in_sizes, int n_in,
                              void* d_out, int out_size, void* d_ws, size_t ws_size,
                              hipStream_t stream){
    const float* df=(const float*)d_in[0];
    const float* lr=(const float*)d_in[1];
    // dict order per i: m1_w i -> d_in[2+4i], m1_b i -> [3+4i], m2_w i -> [4+4i], m2_b i -> [5+4i]
    PrepArgs pa;
    for (int i=0;i<4;++i){
        pa.w[i]   = (const float*)d_in[2+4*(i+1)];   // m1_w1..m1_w4
        pa.b[i]   = (const float*)d_in[3+4*(i+1)];   // m1_b1..m1_b4
        pa.w[4+i] = (const float*)d_in[4+4*(i+1)];   // m2_w1..m2_w4
        pa.b[4+i] = (const float*)d_in[5+4*(i+1)];   // m2_b1..m2_b4
    }
    pa.l1w[0] = (const float*)d_in[2];  pa.l1b[0] = (const float*)d_in[3];
    pa.l1w[1] = (const float*)d_in[4];  pa.l1b[1] = (const float*)d_in[5];

    float* ws = (float*)d_ws;
    hipLaunchKernelGGL(prep_kernel, dim3(131), dim3(256), 0, stream, pa, ws);

    constexpr int NP = 2*359*639;
    hipLaunchKernelGGL(dlut_kernel, dim3((NP+63)/64), dim3(128), 0, stream,
                       df, lr, (const float*)ws, (float*)d_out);
}